// Round 2
// baseline (474.026 us; speedup 1.0000x reference)
//
#include <hip/hip_runtime.h>

constexpr int kB = 32;      // batch
constexpr int kA = 8400;    // anchors total (80*80 + 40*40 + 20*20)
constexpr int kG = 60;      // max GTs
constexpr int kC = 80;      // classes
constexpr int kK = 10;      // top-k

__device__ __forceinline__ float sigm(float x){ return 1.0f/(1.0f+expf(-x)); }

__device__ __forceinline__ float bce(float x, float t){
  // max(x,0) - x*t + log1p(exp(-|x|))
  return fmaxf(x, 0.0f) - x*t + log1pf(expf(-fabsf(x)));
}

struct AInfo { int x, y; float st; };
__device__ __forceinline__ AInfo ainfo(int a){
  AInfo r;
  if (a < 6400)      { r.x = a % 80;           r.y = a / 80;           r.st = 8.0f;  }
  else if (a < 8000) { int l = a-6400; r.x = l % 40; r.y = l / 40;     r.st = 16.0f; }
  else               { int l = a-8000; r.x = l % 20; r.y = l / 20;     r.st = 32.0f; }
  return r;
}

// feat value for (batch b, channel ch, anchor a); layout (B, 85, H, W), a = y*W+x per level
__device__ __forceinline__ float featv(const float* __restrict__ f8,
                                       const float* __restrict__ f16,
                                       const float* __restrict__ f32x,
                                       int b, int ch, int a){
  if (a < 6400) return f8 [(b*85 + ch)*6400 + a];
  if (a < 8000) return f16[(b*85 + ch)*1600 + (a - 6400)];
  return             f32x[(b*85 + ch)*400  + (a - 8000)];
}

// _pair_iou(gt, pred): area_a from gt, denominator (area_a + area_b - inter + 1e-16)
__device__ __forceinline__ float pair_iou(float4 g, float4 p){
  float tlx = fmaxf(g.x - g.z*0.5f, p.x - p.z*0.5f);
  float tly = fmaxf(g.y - g.w*0.5f, p.y - p.w*0.5f);
  float brx = fminf(g.x + g.z*0.5f, p.x + p.z*0.5f);
  float bry = fminf(g.y + g.w*0.5f, p.y + p.w*0.5f);
  float inter = (tlx < brx && tly < bry) ? (brx-tlx)*(bry-tly) : 0.0f;
  return inter / (g.z*g.w + p.z*p.w - inter + 1e-16f);
}

// Full SimOTA cost for (g, a) — shared by k_assign and conflict resolution in k_loss
// so rounding is bit-identical between the two.
__device__ __forceinline__ float cost_at(const float* __restrict__ f8,
                                         const float* __restrict__ f16,
                                         const float* __restrict__ f32x,
                                         int b, int a, float b0sum, float obj_sig, int fg_a,
                                         float4 bx, float4 gt, int cls){
  float iou = pair_iou(gt, bx);
  AInfo ai = ainfo(a);
  float cx = ((float)ai.x + 0.5f)*ai.st;
  float cy = ((float)ai.y + 0.5f)*ai.st;
  bool in_box = (cx > gt.x - 0.5f*gt.z) && (cx < gt.x + 0.5f*gt.z)
             && (cy > gt.y - 0.5f*gt.w) && (cy < gt.y + 0.5f*gt.w);
  bool in_ctr = (cx > gt.x - 2.5f*ai.st) && (cx < gt.x + 2.5f*ai.st)
             && (cy > gt.y - 2.5f*ai.st) && (cy < gt.y + 2.5f*ai.st);
  float cl = featv(f8, f16, f32x, b, 5 + cls, a);
  float p = sqrtf(sigm(cl) * obj_sig);
  p = fminf(fmaxf(p, 1e-7f), 1.0f - 1e-7f);
  float diff = -logf(p) + logf(1.0f - p);      // bce1 - bce0 at class cls
  float c = b0sum + diff;
  c += 3.0f * (-logf(iou + 1e-8f));
  c += (in_box && in_ctr) ? 0.0f : 100000.0f;
  c += fg_a ? 0.0f : 1000000000.0f;
  return c;
}

__global__ void k_zero(float* acc){ if (threadIdx.x < 4) acc[threadIdx.x] = 0.0f; }

__global__ __launch_bounds__(256) void k_decode(
    const float* __restrict__ f8, const float* __restrict__ f16, const float* __restrict__ f32x,
    const float* __restrict__ gtb, const int* __restrict__ ngts,
    float* __restrict__ boxes, float* __restrict__ objl, float* __restrict__ b0s,
    float* __restrict__ bceS,
    int* __restrict__ fg, int* __restrict__ cnt, int* __restrict__ mtch){
  int b = blockIdx.y;
  int a = blockIdx.x*256 + threadIdx.x;
  __shared__ float4 sg[kG];
  if (threadIdx.x < kG) sg[threadIdx.x] = ((const float4*)gtb)[b*kG + threadIdx.x];
  __syncthreads();
  if (a >= kA) return;
  int ng = ngts[b];
  AInfo ai = ainfo(a);
  float t0 = featv(f8,f16,f32x,b,0,a);
  float t1 = featv(f8,f16,f32x,b,1,a);
  float t2 = featv(f8,f16,f32x,b,2,a);
  float t3 = featv(f8,f16,f32x,b,3,a);
  float ob = featv(f8,f16,f32x,b,4,a);
  float4 bx;
  bx.x = (t0 + (float)ai.x) * ai.st;
  bx.y = (t1 + (float)ai.y) * ai.st;
  bx.z = expf(t2) * ai.st;
  bx.w = expf(t3) * ai.st;
  int idx = b*kA + a;
  ((float4*)boxes)[idx] = bx;
  objl[idx] = ob;
  float obs = sigm(ob);
  float s = 0.0f;    // sum of bce0 on geometric-mean prob (for cost)
  float s2 = 0.0f;   // sum of bce(cls_logit, 0) (for loss_cls via linearity in t)
  for (int c = 0; c < kC; ++c){
    float cl = featv(f8,f16,f32x,b,5+c,a);
    float p = sqrtf(sigm(cl)*obs);
    p = fminf(fmaxf(p, 1e-7f), 1.0f - 1e-7f);
    s += -logf(1.0f - p);           // bce0
    s2 += fmaxf(cl, 0.0f) + log1pf(expf(-fabsf(cl)));   // bce(cl, 0)
  }
  b0s[idx] = s;
  bceS[idx] = s2;
  float cx = ((float)ai.x + 0.5f)*ai.st;
  float cy = ((float)ai.y + 0.5f)*ai.st;
  int f = 0;
  for (int g = 0; g < ng; ++g){
    float4 gt = sg[g];
    bool in_box = (cx > gt.x - 0.5f*gt.z) && (cx < gt.x + 0.5f*gt.z)
               && (cy > gt.y - 0.5f*gt.w) && (cy < gt.y + 0.5f*gt.w);
    bool in_ctr = (cx > gt.x - 2.5f*ai.st) && (cx < gt.x + 2.5f*ai.st)
               && (cy > gt.y - 2.5f*ai.st) && (cy < gt.y + 2.5f*ai.st);
    if (in_box || in_ctr){ f = 1; break; }
  }
  fg[idx] = f;
  cnt[idx] = 0;
  mtch[idx] = 0x7fffffff;
}

__global__ __launch_bounds__(256) void k_assign(
    const float* __restrict__ f8, const float* __restrict__ f16, const float* __restrict__ f32x,
    const float* __restrict__ gtb, const int* __restrict__ gtc, const int* __restrict__ ngts,
    const float* __restrict__ boxes, const float* __restrict__ objl, const float* __restrict__ b0s,
    const int* __restrict__ fg, int* __restrict__ cnt, int* __restrict__ mtch){
  int b = blockIdx.x / kG;
  int g = blockIdx.x % kG;
  if (g >= ngts[b]) return;     // vmask: invalid rows contribute nothing
  int tid = threadIdx.x;
  float4 gt = ((const float4*)gtb)[b*kG + g];
  int cls = gtc[b*kG + g];
  __shared__ float sv[kA];      // 33.6 KB row buffer
  __shared__ float rv[256];
  __shared__ int   ri[256];
  __shared__ int   spos[kK];
  __shared__ int   sdynk;
  const float4* bx4 = (const float4*)boxes;

  // ---- pass 1: iou * fg ----
  for (int a = tid; a < kA; a += 256){
    float iou = pair_iou(gt, bx4[b*kA + a]);
    sv[a] = fg[b*kA + a] ? iou : 0.0f;
  }
  __syncthreads();
  float ksum = 0.0f;            // only tid 0's copy is used
  for (int k = 0; k < kK; ++k){
    float bv = -1.0f; int bi = 0x7fffffff;
    for (int a = tid; a < kA; a += 256){
      float v = sv[a];
      if (v > bv || (v == bv && a < bi)){ bv = v; bi = a; }
    }
    rv[tid] = bv; ri[tid] = bi;
    __syncthreads();
    for (int s = 128; s > 0; s >>= 1){
      if (tid < s){
        if (rv[tid+s] > rv[tid] || (rv[tid+s] == rv[tid] && ri[tid+s] < ri[tid])){
          rv[tid] = rv[tid+s]; ri[tid] = ri[tid+s];
        }
      }
      __syncthreads();
    }
    if (tid == 0){ ksum += rv[0]; sv[ri[0]] = -1.0f; }
    __syncthreads();
  }
  if (tid == 0) sdynk = max((int)ksum, 1);   // truncation matches astype(int32)

  // ---- pass 2: cost ----
  for (int a = tid; a < kA; a += 256){
    int idx = b*kA + a;
    float obs = sigm(objl[idx]);
    sv[a] = cost_at(f8,f16,f32x,b,a,b0s[idx],obs,fg[idx],bx4[idx],gt,cls);
  }
  __syncthreads();
  for (int k = 0; k < kK; ++k){
    float bv = 3.0e38f; int bi = 0x7fffffff;
    for (int a = tid; a < kA; a += 256){
      float v = sv[a];
      if (v < bv || (v == bv && a < bi)){ bv = v; bi = a; }
    }
    rv[tid] = bv; ri[tid] = bi;
    __syncthreads();
    for (int s = 128; s > 0; s >>= 1){
      if (tid < s){
        if (rv[tid+s] < rv[tid] || (rv[tid+s] == rv[tid] && ri[tid+s] < ri[tid])){
          rv[tid] = rv[tid+s]; ri[tid] = ri[tid+s];
        }
      }
      __syncthreads();
    }
    if (tid == 0){ spos[k] = ri[0]; sv[ri[0]] = 3.0e38f; }
    __syncthreads();
  }
  if (tid < kK && tid < sdynk){
    int a = spos[tid];
    atomicAdd(&cnt[b*kA + a], 1);
    atomicMin(&mtch[b*kA + a], g);
  }
}

__global__ __launch_bounds__(256) void k_loss(
    const float* __restrict__ f8, const float* __restrict__ f16, const float* __restrict__ f32x,
    const float* __restrict__ gtb, const int* __restrict__ gtc, const int* __restrict__ ngts,
    const float* __restrict__ boxes, const float* __restrict__ objl, const float* __restrict__ b0s,
    const float* __restrict__ bceS,
    const int* __restrict__ fg, const int* __restrict__ cnt, const int* __restrict__ mtch,
    float* __restrict__ acc){
  int b = blockIdx.y;
  int a = blockIdx.x*256 + threadIdx.x;
  int tid = threadIdx.x;
  __shared__ float4 sg[kG];
  __shared__ int scls[kG];
  if (tid < kG){ sg[tid] = ((const float4*)gtb)[b*kG + tid]; scls[tid] = gtc[b*kG + tid]; }
  __syncthreads();
  float li = 0.0f, lo = 0.0f, lc = 0.0f, nf = 0.0f;
  bool valid = (a < kA);
  int idx = valid ? (b*kA + a) : (b*kA);
  int c = valid ? cnt[idx] : 0;
  float ob = valid ? objl[idx] : 0.0f;
  float4 bx = valid ? ((const float4*)boxes)[idx] : make_float4(0,0,1,1);

  float fgf = 0.0f; int mg = 0;
  if (valid && c == 1){ mg = mtch[idx]; fgf = 1.0f; }
  // conflict resolution — wave-uniform skip when no lane conflicts
  bool need = valid && (c > 1);
  if (__any(need)){
    if (need){
      int ng = ngts[b];
      float b0 = b0s[idx];
      float obs = sigm(ob);
      int fga = fg[idx];
      float bestc = 3.0e38f; int bg = 0;
      for (int g = 0; g < ng; ++g){
        float cst = cost_at(f8,f16,f32x,b,a,b0,obs,fga,bx,sg[g],scls[g]);
        if (cst < bestc){ bestc = cst; bg = g; }   // strict < : first min = jnp.argmin
      }
      mg = bg; fgf = 1.0f;
    }
  }
  if (valid){
    lo = bce(ob, fgf*0.9f);
    if (fgf > 0.0f){
      nf = 1.0f;
      float4 r = sg[mg];
      float piou = pair_iou(r, bx);
      // _iou_loss
      float tlx = fmaxf(bx.x - bx.z*0.5f, r.x - r.z*0.5f);
      float tly = fmaxf(bx.y - bx.w*0.5f, r.y - r.w*0.5f);
      float brx = fminf(bx.x + bx.z*0.5f, r.x + r.z*0.5f);
      float bry = fminf(bx.y + bx.w*0.5f, r.y + r.w*0.5f);
      float inter = (tlx < brx && tly < bry) ? (brx-tlx)*(bry-tly) : 0.0f;
      float un = bx.z*bx.w + r.z*r.w - inter;
      float iou = inter / (un + 1e-16f);
      li = 1.0f - iou*iou;
      // loss_cls via linearity: sum_c bce(cl,t_c) = sum_c bce(cl,0) - piou * cl_tc
      int tc = scls[mg];
      float cl_tc = featv(f8,f16,f32x,b,5+tc,a);
      lc = bceS[idx] - piou * cl_tc;
    }
  }
  // wave shuffle reduction (64 lanes), then cross-wave via LDS
  for (int off = 32; off > 0; off >>= 1){
    li += __shfl_down(li, off, 64);
    lo += __shfl_down(lo, off, 64);
    lc += __shfl_down(lc, off, 64);
    nf += __shfl_down(nf, off, 64);
  }
  __shared__ float4 wred[4];
  int wid = tid >> 6;
  if ((tid & 63) == 0) wred[wid] = make_float4(li, lo, lc, nf);
  __syncthreads();
  if (tid == 0){
    float4 t = wred[0];
    for (int w = 1; w < 4; ++w){
      float4 o = wred[w];
      t.x += o.x; t.y += o.y; t.z += o.z; t.w += o.w;
    }
    atomicAdd(&acc[0], t.x);
    atomicAdd(&acc[1], t.y);
    atomicAdd(&acc[2], t.z);
    atomicAdd(&acc[3], t.w);
  }
}

__global__ void k_final(const float* __restrict__ acc, float* __restrict__ out){
  out[0] = (5.0f*acc[0] + acc[1] + acc[2]) / fmaxf(acc[3], 1.0f);
}

extern "C" void kernel_launch(void* const* d_in, const int* in_sizes, int n_in,
                              void* d_out, int out_size, void* d_ws, size_t ws_size,
                              hipStream_t stream) {
  (void)in_sizes; (void)n_in; (void)out_size; (void)ws_size;
  const float* f8   = (const float*)d_in[0];
  const float* f16  = (const float*)d_in[1];
  const float* f32x = (const float*)d_in[2];
  const float* gtb  = (const float*)d_in[3];
  const int*   gtc  = (const int*)d_in[4];
  const int*   ngts = (const int*)d_in[5];
  float* out = (float*)d_out;

  float* ws    = (float*)d_ws;
  float* boxes = ws;                              // B*A*4
  float* objl  = boxes + (size_t)kB*kA*4;         // B*A
  float* b0s   = objl  + (size_t)kB*kA;           // B*A
  float* bceS  = b0s   + (size_t)kB*kA;           // B*A
  int*   fg    = (int*)(bceS + (size_t)kB*kA);    // B*A
  int*   cnt   = fg  + (size_t)kB*kA;             // B*A
  int*   mtch  = cnt + (size_t)kB*kA;             // B*A
  float* acc   = (float*)(mtch + (size_t)kB*kA);  // 4

  dim3 gBA((kA + 255)/256, kB);
  k_zero<<<dim3(1), dim3(64), 0, stream>>>(acc);
  k_decode<<<gBA, dim3(256), 0, stream>>>(f8,f16,f32x,gtb,ngts,boxes,objl,b0s,bceS,fg,cnt,mtch);
  k_assign<<<dim3(kB*kG), dim3(256), 0, stream>>>(f8,f16,f32x,gtb,gtc,ngts,boxes,objl,b0s,fg,cnt,mtch);
  k_loss<<<gBA, dim3(256), 0, stream>>>(f8,f16,f32x,gtb,gtc,ngts,boxes,objl,b0s,bceS,fg,cnt,mtch,acc);
  k_final<<<dim3(1), dim3(1), 0, stream>>>(acc, out);
}

// Round 3
// 330.612 us; speedup vs baseline: 1.4338x; 1.4338x over previous
//
#include <hip/hip_runtime.h>

constexpr int kB = 32;      // batch
constexpr int kA = 8400;    // anchors total (80*80 + 40*40 + 20*20)
constexpr int kG = 60;      // max GTs
constexpr int kC = 80;      // classes
constexpr int kK = 10;      // top-k

// ---- HW-native fast math (v_exp_f32 / v_log_f32 / v_rcp_f32 / v_sqrt_f32) ----
__device__ __forceinline__ float fexp(float x){ return __expf(x); }
__device__ __forceinline__ float flog(float x){ return __logf(x); }
__device__ __forceinline__ float frcp(float x){ return __builtin_amdgcn_rcpf(x); }
__device__ __forceinline__ float fsqrt(float x){ return __builtin_amdgcn_sqrtf(x); }
__device__ __forceinline__ float fdiv(float a, float b){ return a * __builtin_amdgcn_rcpf(b); }
__device__ __forceinline__ float sigm(float x){ return frcp(1.0f + fexp(-x)); }
__device__ __forceinline__ float bce(float x, float t){
  return fmaxf(x, 0.0f) - x*t + flog(1.0f + fexp(-fabsf(x)));
}

// ordered-bits transform: monotone map float -> u32 (total order)
__device__ __forceinline__ unsigned ordbits(float v){
  unsigned u = __float_as_uint(v);
  return (u & 0x80000000u) ? ~u : (u | 0x80000000u);
}
__device__ __forceinline__ float unpackf(unsigned k){
  return __uint_as_float((k & 0x80000000u) ? (k & 0x7fffffffu) : ~k);
}

struct AInfo { int x, y; float st; };
__device__ __forceinline__ AInfo ainfo(int a){
  AInfo r;
  if (a < 6400)      { r.x = a % 80;           r.y = a / 80;           r.st = 8.0f;  }
  else if (a < 8000) { int l = a-6400; r.x = l % 40; r.y = l / 40;     r.st = 16.0f; }
  else               { int l = a-8000; r.x = l % 20; r.y = l / 20;     r.st = 32.0f; }
  return r;
}

__device__ __forceinline__ float featv(const float* __restrict__ f8,
                                       const float* __restrict__ f16,
                                       const float* __restrict__ f32x,
                                       int b, int ch, int a){
  if (a < 6400) return f8 [(b*85 + ch)*6400 + a];
  if (a < 8000) return f16[(b*85 + ch)*1600 + (a - 6400)];
  return             f32x[(b*85 + ch)*400  + (a - 8000)];
}

__device__ __forceinline__ float pair_iou(float4 g, float4 p){
  float tlx = fmaxf(g.x - g.z*0.5f, p.x - p.z*0.5f);
  float tly = fmaxf(g.y - g.w*0.5f, p.y - p.w*0.5f);
  float brx = fminf(g.x + g.z*0.5f, p.x + p.z*0.5f);
  float bry = fminf(g.y + g.w*0.5f, p.y + p.w*0.5f);
  float inter = (tlx < brx && tly < bry) ? (brx-tlx)*(bry-tly) : 0.0f;
  return fdiv(inter, g.z*g.w + p.z*p.w - inter + 1e-16f);
}

// Full SimOTA cost — shared by k_assign and k_loss conflict path (bit-identical).
__device__ __forceinline__ float cost_at(const float* __restrict__ f8,
                                         const float* __restrict__ f16,
                                         const float* __restrict__ f32x,
                                         int b, int a, float b0sum, float obj_sig, int fg_a,
                                         float4 bx, float4 gt, int cls){
  float iou = pair_iou(gt, bx);
  AInfo ai = ainfo(a);
  float cx = ((float)ai.x + 0.5f)*ai.st;
  float cy = ((float)ai.y + 0.5f)*ai.st;
  bool in_box = (cx > gt.x - 0.5f*gt.z) && (cx < gt.x + 0.5f*gt.z)
             && (cy > gt.y - 0.5f*gt.w) && (cy < gt.y + 0.5f*gt.w);
  bool in_ctr = (cx > gt.x - 2.5f*ai.st) && (cx < gt.x + 2.5f*ai.st)
             && (cy > gt.y - 2.5f*ai.st) && (cy < gt.y + 2.5f*ai.st);
  float cl = featv(f8, f16, f32x, b, 5 + cls, a);
  float p = fsqrt(sigm(cl) * obj_sig);
  p = fminf(fmaxf(p, 1e-7f), 1.0f - 1e-7f);
  float diff = -flog(p) + flog(1.0f - p);      // bce1 - bce0 at class cls
  float c = b0sum + diff;
  c += 3.0f * (-flog(iou + 1e-8f));
  c += (in_box && in_ctr) ? 0.0f : 100000.0f;
  c += fg_a ? 0.0f : 1000000000.0f;
  return c;
}

__global__ void k_zero(float* acc){ if (threadIdx.x < 4) acc[threadIdx.x] = 0.0f; }

__global__ __launch_bounds__(256) void k_decode(
    const float* __restrict__ f8, const float* __restrict__ f16, const float* __restrict__ f32x,
    const float* __restrict__ gtb, const int* __restrict__ ngts,
    float* __restrict__ boxes, float* __restrict__ objl, float* __restrict__ b0s,
    float* __restrict__ bceS,
    int* __restrict__ fg, int* __restrict__ cnt, int* __restrict__ mtch){
  int b = blockIdx.y;
  int tid = threadIdx.x;
  int a = blockIdx.x*256 + tid;
  __shared__ float4 sg[kG];
  if (tid < kG) sg[tid] = ((const float4*)gtb)[b*kG + tid];
  __syncthreads();
  if (a >= kA) return;
  int ng = ngts[b];
  const float* base; int hw, off; float st_; int gx, gy;
  if (a < 6400)      { base=f8;   hw=6400; off=a;        st_=8.0f;  gx=off%80; gy=off/80; }
  else if (a < 8000) { base=f16;  hw=1600; off=a-6400;   st_=16.0f; gx=off%40; gy=off/40; }
  else               { base=f32x; hw=400;  off=a-8000;   st_=32.0f; gx=off%20; gy=off/20; }
  const float* p0 = base + ((size_t)b*85)*hw + off;
  float t0 = p0[0];
  float t1 = p0[(size_t)hw];
  float t2 = p0[(size_t)2*hw];
  float t3 = p0[(size_t)3*hw];
  float ob = p0[(size_t)4*hw];
  float4 bx;
  bx.x = (t0 + (float)gx) * st_;
  bx.y = (t1 + (float)gy) * st_;
  bx.z = fexp(t2) * st_;
  bx.w = fexp(t3) * st_;
  int idx = b*kA + a;
  ((float4*)boxes)[idx] = bx;
  objl[idx] = ob;
  float obs = sigm(ob);
  float s = 0.0f;    // sum bce0 on geometric-mean prob (cost base)
  float s2 = 0.0f;   // sum bce(cl, 0) (loss_cls via linearity in t)
  const float* pc = p0 + (size_t)5*hw;
  #pragma unroll 4
  for (int c = 0; c < kC; ++c){
    float cl = pc[(size_t)c*hw];
    float p = fsqrt(sigm(cl)*obs);
    p = fminf(fmaxf(p, 1e-7f), 1.0f - 1e-7f);
    s -= flog(1.0f - p);
    s2 += fmaxf(cl, 0.0f) + flog(1.0f + fexp(-fabsf(cl)));
  }
  b0s[idx] = s;
  bceS[idx] = s2;
  float cx = ((float)gx + 0.5f)*st_;
  float cy = ((float)gy + 0.5f)*st_;
  int f = 0;
  for (int g = 0; g < ng; ++g){
    float4 gt = sg[g];
    bool in_box = (cx > gt.x - 0.5f*gt.z) && (cx < gt.x + 0.5f*gt.z)
               && (cy > gt.y - 0.5f*gt.w) && (cy < gt.y + 0.5f*gt.w);
    bool in_ctr = (cx > gt.x - 2.5f*st_) && (cx < gt.x + 2.5f*st_)
               && (cy > gt.y - 2.5f*st_) && (cy < gt.y + 2.5f*st_);
    if (in_box || in_ctr){ f = 1; break; }
  }
  fg[idx] = f;
  cnt[idx] = 0;
  mtch[idx] = 0x7fffffff;
}

__global__ __launch_bounds__(256) void k_assign(
    const float* __restrict__ f8, const float* __restrict__ f16, const float* __restrict__ f32x,
    const float* __restrict__ gtb, const int* __restrict__ gtc, const int* __restrict__ ngts,
    const float* __restrict__ boxes, const float* __restrict__ objl, const float* __restrict__ b0s,
    const int* __restrict__ fg, int* __restrict__ cnt, int* __restrict__ mtch){
  int b = blockIdx.x / kG;
  int g = blockIdx.x % kG;
  if (g >= ngts[b]) return;     // vmask
  int tid = threadIdx.x;
  int lane = tid & 63, wid = tid >> 6;
  float4 gt = ((const float4*)gtb)[b*kG + g];
  int cls = gtc[b*kG + g];
  const float4* bx4 = (const float4*)boxes;
  __shared__ unsigned long long wk[4];

  // ---- pass 1: per-thread top-10 of iou*fg (max keys; tie -> smaller index) ----
  unsigned long long kept[kK];
  #pragma unroll
  for (int i = 0; i < kK; ++i) kept[i] = 0ull;
  for (int a = tid; a < kA; a += 256){
    float iou = pair_iou(gt, bx4[b*kA + a]);
    float v = fg[b*kA + a] ? iou : 0.0f;
    unsigned long long key = ((unsigned long long)ordbits(v) << 32) | (unsigned)(~a);
    if (key > kept[kK-1]){
      kept[kK-1] = key;
      #pragma unroll
      for (int i = kK-1; i > 0; --i){
        if (kept[i] > kept[i-1]){ unsigned long long t = kept[i]; kept[i] = kept[i-1]; kept[i-1] = t; }
      }
    }
  }
  float ksum = 0.0f;
  for (int k = 0; k < kK; ++k){
    unsigned long long best = kept[0];
    #pragma unroll
    for (int off = 32; off; off >>= 1){
      unsigned long long o = __shfl_xor(best, off, 64);
      if (o > best) best = o;
    }
    if (lane == 0) wk[wid] = best;
    __syncthreads();
    unsigned long long w0 = wk[0];
    if (wk[1] > w0) w0 = wk[1];
    if (wk[2] > w0) w0 = wk[2];
    if (wk[3] > w0) w0 = wk[3];
    if (kept[0] == w0){              // keys unique (index bits) -> exactly one pop
      #pragma unroll
      for (int i = 0; i < kK-1; ++i) kept[i] = kept[i+1];
      kept[kK-1] = 0ull;
    }
    ksum += unpackf((unsigned)(w0 >> 32));   // descending order, matches top_k sum
    __syncthreads();
  }
  int dynk = max((int)ksum, 1);    // truncation matches astype(int32)

  // ---- pass 2: per-thread bottom-10 of cost (min; tie -> smaller index) ----
  // min-reduce expressed as max-reduce on complemented keys
  #pragma unroll
  for (int i = 0; i < kK; ++i) kept[i] = 0ull;
  for (int a = tid; a < kA; a += 256){
    int idx = b*kA + a;
    float obs = sigm(objl[idx]);
    float c = cost_at(f8,f16,f32x,b,a,b0s[idx],obs,fg[idx],bx4[idx],gt,cls);
    unsigned long long key = ~(((unsigned long long)ordbits(c) << 32) | (unsigned)a);
    if (key > kept[kK-1]){
      kept[kK-1] = key;
      #pragma unroll
      for (int i = kK-1; i > 0; --i){
        if (kept[i] > kept[i-1]){ unsigned long long t = kept[i]; kept[i] = kept[i-1]; kept[i-1] = t; }
      }
    }
  }
  int my_a = -1;
  for (int k = 0; k < kK; ++k){
    unsigned long long best = kept[0];
    #pragma unroll
    for (int off = 32; off; off >>= 1){
      unsigned long long o = __shfl_xor(best, off, 64);
      if (o > best) best = o;
    }
    if (lane == 0) wk[wid] = best;
    __syncthreads();
    unsigned long long w0 = wk[0];
    if (wk[1] > w0) w0 = wk[1];
    if (wk[2] > w0) w0 = wk[2];
    if (wk[3] > w0) w0 = wk[3];
    if (kept[0] == w0){
      #pragma unroll
      for (int i = 0; i < kK-1; ++i) kept[i] = kept[i+1];
      kept[kK-1] = 0ull;
    }
    if (tid == k) my_a = (int)((unsigned)(~w0) & 0xffffffffu);
    __syncthreads();
  }
  if (tid < kK && tid < dynk){
    atomicAdd(&cnt[b*kA + my_a], 1);
    atomicMin(&mtch[b*kA + my_a], g);
  }
}

__global__ __launch_bounds__(256) void k_loss(
    const float* __restrict__ f8, const float* __restrict__ f16, const float* __restrict__ f32x,
    const float* __restrict__ gtb, const int* __restrict__ gtc, const int* __restrict__ ngts,
    const float* __restrict__ boxes, const float* __restrict__ objl, const float* __restrict__ b0s,
    const float* __restrict__ bceS,
    const int* __restrict__ fg, const int* __restrict__ cnt, const int* __restrict__ mtch,
    float* __restrict__ acc){
  int b = blockIdx.y;
  int a = blockIdx.x*256 + threadIdx.x;
  int tid = threadIdx.x;
  __shared__ float4 sg[kG];
  __shared__ int scls[kG];
  if (tid < kG){ sg[tid] = ((const float4*)gtb)[b*kG + tid]; scls[tid] = gtc[b*kG + tid]; }
  __syncthreads();
  float li = 0.0f, lo = 0.0f, lc = 0.0f, nf = 0.0f;
  bool valid = (a < kA);
  int idx = valid ? (b*kA + a) : (b*kA);
  int c = valid ? cnt[idx] : 0;
  float ob = valid ? objl[idx] : 0.0f;
  float4 bx = valid ? ((const float4*)boxes)[idx] : make_float4(0,0,1,1);

  float fgf = 0.0f; int mg = 0;
  if (valid && c == 1){ mg = mtch[idx]; fgf = 1.0f; }
  bool need = valid && (c > 1);
  if (__any(need)){
    if (need){
      int ng = ngts[b];
      float b0 = b0s[idx];
      float obs = sigm(ob);
      int fga = fg[idx];
      float bestc = 3.0e38f; int bg = 0;
      for (int g = 0; g < ng; ++g){
        float cst = cost_at(f8,f16,f32x,b,a,b0,obs,fga,bx,sg[g],scls[g]);
        if (cst < bestc){ bestc = cst; bg = g; }   // strict <: first min = jnp.argmin
      }
      mg = bg; fgf = 1.0f;
    }
  }
  if (valid){
    lo = bce(ob, fgf*0.9f);
    if (fgf > 0.0f){
      nf = 1.0f;
      float4 r = sg[mg];
      float piou = pair_iou(r, bx);
      float tlx = fmaxf(bx.x - bx.z*0.5f, r.x - r.z*0.5f);
      float tly = fmaxf(bx.y - bx.w*0.5f, r.y - r.w*0.5f);
      float brx = fminf(bx.x + bx.z*0.5f, r.x + r.z*0.5f);
      float bry = fminf(bx.y + bx.w*0.5f, r.y + r.w*0.5f);
      float inter = (tlx < brx && tly < bry) ? (brx-tlx)*(bry-tly) : 0.0f;
      float un = bx.z*bx.w + r.z*r.w - inter;
      float iou = fdiv(inter, un + 1e-16f);
      li = 1.0f - iou*iou;
      int tc = scls[mg];
      float cl_tc = featv(f8,f16,f32x,b,5+tc,a);
      lc = bceS[idx] - piou * cl_tc;   // linearity of bce in target
    }
  }
  for (int off = 32; off > 0; off >>= 1){
    li += __shfl_down(li, off, 64);
    lo += __shfl_down(lo, off, 64);
    lc += __shfl_down(lc, off, 64);
    nf += __shfl_down(nf, off, 64);
  }
  __shared__ float4 wred[4];
  int wid = tid >> 6;
  if ((tid & 63) == 0) wred[wid] = make_float4(li, lo, lc, nf);
  __syncthreads();
  if (tid == 0){
    float4 t = wred[0];
    for (int w = 1; w < 4; ++w){
      float4 o = wred[w];
      t.x += o.x; t.y += o.y; t.z += o.z; t.w += o.w;
    }
    atomicAdd(&acc[0], t.x);
    atomicAdd(&acc[1], t.y);
    atomicAdd(&acc[2], t.z);
    atomicAdd(&acc[3], t.w);
  }
}

__global__ void k_final(const float* __restrict__ acc, float* __restrict__ out){
  out[0] = (5.0f*acc[0] + acc[1] + acc[2]) / fmaxf(acc[3], 1.0f);
}

extern "C" void kernel_launch(void* const* d_in, const int* in_sizes, int n_in,
                              void* d_out, int out_size, void* d_ws, size_t ws_size,
                              hipStream_t stream) {
  (void)in_sizes; (void)n_in; (void)out_size; (void)ws_size;
  const float* f8   = (const float*)d_in[0];
  const float* f16  = (const float*)d_in[1];
  const float* f32x = (const float*)d_in[2];
  const float* gtb  = (const float*)d_in[3];
  const int*   gtc  = (const int*)d_in[4];
  const int*   ngts = (const int*)d_in[5];
  float* out = (float*)d_out;

  float* ws    = (float*)d_ws;
  float* boxes = ws;                              // B*A*4
  float* objl  = boxes + (size_t)kB*kA*4;         // B*A
  float* b0s   = objl  + (size_t)kB*kA;           // B*A
  float* bceS  = b0s   + (size_t)kB*kA;           // B*A
  int*   fg    = (int*)(bceS + (size_t)kB*kA);    // B*A
  int*   cnt   = fg  + (size_t)kB*kA;             // B*A
  int*   mtch  = cnt + (size_t)kB*kA;             // B*A
  float* acc   = (float*)(mtch + (size_t)kB*kA);  // 4

  dim3 gBA((kA + 255)/256, kB);
  k_zero<<<dim3(1), dim3(64), 0, stream>>>(acc);
  k_decode<<<gBA, dim3(256), 0, stream>>>(f8,f16,f32x,gtb,ngts,boxes,objl,b0s,bceS,fg,cnt,mtch);
  k_assign<<<dim3(kB*kG), dim3(256), 0, stream>>>(f8,f16,f32x,gtb,gtc,ngts,boxes,objl,b0s,fg,cnt,mtch);
  k_loss<<<gBA, dim3(256), 0, stream>>>(f8,f16,f32x,gtb,gtc,ngts,boxes,objl,b0s,bceS,fg,cnt,mtch,acc);
  k_final<<<dim3(1), dim3(1), 0, stream>>>(acc, out);
}

// Round 4
// 277.289 us; speedup vs baseline: 1.7095x; 1.1923x over previous
//
#include <hip/hip_runtime.h>

constexpr int kB = 32;      // batch
constexpr int kA = 8400;    // anchors total (80*80 + 40*40 + 20*20)
constexpr int kG = 60;      // max GTs
constexpr int kC = 80;      // classes
constexpr int kK = 10;      // top-k

// ---- HW-native fast math ----
__device__ __forceinline__ float fexp(float x){ return __expf(x); }
__device__ __forceinline__ float flog(float x){ return __logf(x); }
__device__ __forceinline__ float frcp(float x){ return __builtin_amdgcn_rcpf(x); }
__device__ __forceinline__ float fsqrt(float x){ return __builtin_amdgcn_sqrtf(x); }
__device__ __forceinline__ float fdiv(float a, float b){ return a * __builtin_amdgcn_rcpf(b); }
__device__ __forceinline__ float sigm(float x){ return frcp(1.0f + fexp(-x)); }
__device__ __forceinline__ float bce(float x, float t){
  return fmaxf(x, 0.0f) - x*t + flog(1.0f + fexp(-fabsf(x)));
}

// monotone float -> u32 (total order)
__device__ __forceinline__ unsigned ordbits(float v){
  unsigned u = __float_as_uint(v);
  return (u & 0x80000000u) ? ~u : (u | 0x80000000u);
}
__device__ __forceinline__ float unpackf(unsigned k){
  return __uint_as_float((k & 0x80000000u) ? (k & 0x7fffffffu) : ~k);
}

struct AInfo { int x, y; float st; };
__device__ __forceinline__ AInfo ainfo(int a){
  AInfo r;
  if (a < 6400)      { r.x = a % 80;           r.y = a / 80;           r.st = 8.0f;  }
  else if (a < 8000) { int l = a-6400; r.x = l % 40; r.y = l / 40;     r.st = 16.0f; }
  else               { int l = a-8000; r.x = l % 20; r.y = l / 20;     r.st = 32.0f; }
  return r;
}

__device__ __forceinline__ float featv(const float* __restrict__ f8,
                                       const float* __restrict__ f16,
                                       const float* __restrict__ f32x,
                                       int b, int ch, int a){
  if (a < 6400) return f8 [(b*85 + ch)*6400 + a];
  if (a < 8000) return f16[(b*85 + ch)*1600 + (a - 6400)];
  return             f32x[(b*85 + ch)*400  + (a - 8000)];
}

__device__ __forceinline__ float pair_iou(float4 g, float4 p){
  float tlx = fmaxf(g.x - g.z*0.5f, p.x - p.z*0.5f);
  float tly = fmaxf(g.y - g.w*0.5f, p.y - p.w*0.5f);
  float brx = fminf(g.x + g.z*0.5f, p.x + p.z*0.5f);
  float bry = fminf(g.y + g.w*0.5f, p.y + p.w*0.5f);
  float inter = (tlx < brx && tly < bry) ? (brx-tlx)*(bry-tly) : 0.0f;
  return fdiv(inter, g.z*g.w + p.z*p.w - inter + 1e-16f);
}

// cost given precomputed iou and obj sigmoid — shared by k_assign / k_loss
__device__ __forceinline__ float cost_core(float iou, float cl, float obs, float b0sum,
                                           int a, float4 gt, int fg_a){
  AInfo ai = ainfo(a);
  float cx = ((float)ai.x + 0.5f)*ai.st;
  float cy = ((float)ai.y + 0.5f)*ai.st;
  bool in_box = (cx > gt.x - 0.5f*gt.z) && (cx < gt.x + 0.5f*gt.z)
             && (cy > gt.y - 0.5f*gt.w) && (cy < gt.y + 0.5f*gt.w);
  bool in_ctr = (cx > gt.x - 2.5f*ai.st) && (cx < gt.x + 2.5f*ai.st)
             && (cy > gt.y - 2.5f*ai.st) && (cy < gt.y + 2.5f*ai.st);
  float p = fsqrt(sigm(cl) * obs);
  p = fminf(fmaxf(p, 1e-7f), 1.0f - 1e-7f);
  float diff = -flog(p) + flog(1.0f - p);      // bce1 - bce0 at class cls
  float c = b0sum + diff;
  c += 3.0f * (-flog(iou + 1e-8f));
  c += (in_box && in_ctr) ? 0.0f : 100000.0f;
  c += fg_a ? 0.0f : 1000000000.0f;
  return c;
}

__global__ void k_zero(float* acc){ if (threadIdx.x < 4) acc[threadIdx.x] = 0.0f; }

__global__ __launch_bounds__(256) void k_decode(
    const float* __restrict__ f8, const float* __restrict__ f16, const float* __restrict__ f32x,
    const float* __restrict__ gtb, const int* __restrict__ ngts,
    float* __restrict__ boxes, float* __restrict__ objl, float* __restrict__ b0s,
    float* __restrict__ bceS, float* __restrict__ obsA,
    int* __restrict__ fg, int* __restrict__ cnt, int* __restrict__ mtch){
  int b = blockIdx.y;
  int tid = threadIdx.x;
  int a = blockIdx.x*256 + tid;
  __shared__ float4 sg[kG];
  if (tid < kG) sg[tid] = ((const float4*)gtb)[b*kG + tid];
  __syncthreads();
  if (a >= kA) return;
  int ng = ngts[b];
  const float* base; int hw, off; float st_; int gx, gy;
  if (a < 6400)      { base=f8;   hw=6400; off=a;        st_=8.0f;  gx=off%80; gy=off/80; }
  else if (a < 8000) { base=f16;  hw=1600; off=a-6400;   st_=16.0f; gx=off%40; gy=off/40; }
  else               { base=f32x; hw=400;  off=a-8000;   st_=32.0f; gx=off%20; gy=off/20; }
  const float* p0 = base + ((size_t)b*85)*hw + off;
  float t0 = p0[0];
  float t1 = p0[(size_t)hw];
  float t2 = p0[(size_t)2*hw];
  float t3 = p0[(size_t)3*hw];
  float ob = p0[(size_t)4*hw];
  float4 bx;
  bx.x = (t0 + (float)gx) * st_;
  bx.y = (t1 + (float)gy) * st_;
  bx.z = fexp(t2) * st_;
  bx.w = fexp(t3) * st_;
  int idx = b*kA + a;
  ((float4*)boxes)[idx] = bx;
  objl[idx] = ob;
  float obs = sigm(ob);
  obsA[idx] = obs;
  float s = 0.0f;    // sum bce0 on geometric-mean prob (cost base)
  float s2 = 0.0f;   // sum bce(cl, 0) (loss_cls via linearity in t)
  const float* pc = p0 + (size_t)5*hw;
  #pragma unroll 4
  for (int c = 0; c < kC; ++c){
    float cl = pc[(size_t)c*hw];
    float p = fsqrt(sigm(cl)*obs);
    p = fminf(fmaxf(p, 1e-7f), 1.0f - 1e-7f);
    s -= flog(1.0f - p);
    s2 += fmaxf(cl, 0.0f) + flog(1.0f + fexp(-fabsf(cl)));
  }
  b0s[idx] = s;
  bceS[idx] = s2;
  float cx = ((float)gx + 0.5f)*st_;
  float cy = ((float)gy + 0.5f)*st_;
  int f = 0;
  for (int g = 0; g < ng; ++g){
    float4 gt = sg[g];
    bool in_box = (cx > gt.x - 0.5f*gt.z) && (cx < gt.x + 0.5f*gt.z)
               && (cy > gt.y - 0.5f*gt.w) && (cy < gt.y + 0.5f*gt.w);
    bool in_ctr = (cx > gt.x - 2.5f*st_) && (cx < gt.x + 2.5f*st_)
               && (cy > gt.y - 2.5f*st_) && (cy < gt.y + 2.5f*st_);
    if (in_box || in_ctr){ f = 1; break; }
  }
  fg[idx] = f;
  cnt[idx] = 0;
  mtch[idx] = 0x7fffffff;
}

// ordered compaction of fg anchors: one block per batch; preserves ascending index order
__global__ __launch_bounds__(1024) void k_compact(
    const int* __restrict__ fg, unsigned short* __restrict__ alist, int* __restrict__ mcnt){
  int b = blockIdx.x;
  int tid = threadIdx.x;
  const int CH = 9;                       // ceil(8400/1024)
  int start = tid*CH;
  int myf[CH]; int cl = 0;
  #pragma unroll
  for (int j = 0; j < CH; ++j){
    int a = start + j;
    int f = (a < kA) ? fg[b*kA + a] : 0;
    myf[j] = f; cl += f;
  }
  __shared__ int s1[1024], s2[1024];
  int* cur = s1; int* nxt = s2;
  cur[tid] = cl; __syncthreads();
  for (int off = 1; off < 1024; off <<= 1){
    int v = cur[tid];
    if (tid >= off) v += cur[tid - off];
    nxt[tid] = v; __syncthreads();
    int* t = cur; cur = nxt; nxt = t;
  }
  int o = cur[tid] - cl;                  // exclusive prefix
  unsigned short* out = alist + (size_t)b*kA;
  #pragma unroll
  for (int j = 0; j < CH; ++j){
    int a = start + j;
    if (a < kA && myf[j]) out[o++] = (unsigned short)a;
  }
  if (tid == 1023) mcnt[b] = cur[tid];
}

__global__ __launch_bounds__(256) void k_assign(
    const float* __restrict__ f8, const float* __restrict__ f16, const float* __restrict__ f32x,
    const float* __restrict__ gtb, const int* __restrict__ gtc, const int* __restrict__ ngts,
    const float* __restrict__ boxes, const float* __restrict__ obsA, const float* __restrict__ b0s,
    const int* __restrict__ fg, const unsigned short* __restrict__ alist, const int* __restrict__ mcnt,
    int* __restrict__ cnt, int* __restrict__ mtch){
  int b = blockIdx.x / kG;
  int g = blockIdx.x % kG;
  if (g >= ngts[b]) return;     // vmask (block-uniform)
  int tid = threadIdx.x;
  int lane = tid & 63, wid = tid >> 6;
  float4 gt = ((const float4*)gtb)[b*kG + g];
  int cls = gtc[b*kG + g];
  const float4* bx4 = (const float4*)boxes;
  // per-level channel base pointers for class `cls`
  const float* c8  = f8   + ((size_t)b*85 + 5 + cls)*6400;
  const float* c16 = f16  + ((size_t)b*85 + 5 + cls)*1600;
  const float* c32 = f32x + ((size_t)b*85 + 5 + cls)*400;
  int m = mcnt[b];
  bool full = (m < kK);          // fallback: scan everything (exactness guard)
  int len = full ? kA : m;
  const unsigned short* al = alist + (size_t)b*kA;
  __shared__ unsigned long long wk[4];

  unsigned long long k1[kK], k2[kK];   // pass1 max-keys, pass2 (complemented) min-keys
  #pragma unroll
  for (int i = 0; i < kK; ++i){ k1[i] = 0ull; k2[i] = 0ull; }

  for (int i = tid; i < len; i += 256){
    int a = full ? i : (int)al[i];
    int idx = b*kA + a;
    float4 bx = bx4[idx];
    float iou = pair_iou(gt, bx);
    int fga = full ? fg[idx] : 1;
    // pass-1 key: value = iou*fg, tie -> smaller index
    float v = fga ? iou : 0.0f;
    unsigned long long key1 = ((unsigned long long)ordbits(v) << 32) | (unsigned)(~a);
    if (key1 > k1[kK-1]){
      k1[kK-1] = key1;
      #pragma unroll
      for (int i2 = kK-1; i2 > 0; --i2)
        if (k1[i2] > k1[i2-1]){ unsigned long long t = k1[i2]; k1[i2] = k1[i2-1]; k1[i2-1] = t; }
    }
    // pass-2 key: min cost, tie -> smaller index (complemented for max-reduce)
    float cl = (a < 6400) ? c8[a] : (a < 8000) ? c16[a-6400] : c32[a-8000];
    float c = cost_core(iou, cl, obsA[idx], b0s[idx], a, gt, fga);
    unsigned long long key2 = ~(((unsigned long long)ordbits(c) << 32) | (unsigned)a);
    if (key2 > k2[kK-1]){
      k2[kK-1] = key2;
      #pragma unroll
      for (int i2 = kK-1; i2 > 0; --i2)
        if (k2[i2] > k2[i2-1]){ unsigned long long t = k2[i2]; k2[i2] = k2[i2-1]; k2[i2-1] = t; }
    }
  }

  // extract global top-10 of pass-1 (sum of values, descending order)
  float ksum = 0.0f;
  for (int k = 0; k < kK; ++k){
    unsigned long long best = k1[0];
    #pragma unroll
    for (int off = 32; off; off >>= 1){
      unsigned long long o = __shfl_xor(best, off, 64);
      if (o > best) best = o;
    }
    if (lane == 0) wk[wid] = best;
    __syncthreads();
    unsigned long long w0 = wk[0];
    if (wk[1] > w0) w0 = wk[1];
    if (wk[2] > w0) w0 = wk[2];
    if (wk[3] > w0) w0 = wk[3];
    if (k1[0] == w0){                     // unique keys -> exactly one pop
      #pragma unroll
      for (int i = 0; i < kK-1; ++i) k1[i] = k1[i+1];
      k1[kK-1] = 0ull;
    }
    ksum += unpackf((unsigned)(w0 >> 32));
    __syncthreads();
  }
  int dynk = max((int)ksum, 1);

  // extract global bottom-10 of cost
  int my_a = -1;
  for (int k = 0; k < kK; ++k){
    unsigned long long best = k2[0];
    #pragma unroll
    for (int off = 32; off; off >>= 1){
      unsigned long long o = __shfl_xor(best, off, 64);
      if (o > best) best = o;
    }
    if (lane == 0) wk[wid] = best;
    __syncthreads();
    unsigned long long w0 = wk[0];
    if (wk[1] > w0) w0 = wk[1];
    if (wk[2] > w0) w0 = wk[2];
    if (wk[3] > w0) w0 = wk[3];
    if (k2[0] == w0){
      #pragma unroll
      for (int i = 0; i < kK-1; ++i) k2[i] = k2[i+1];
      k2[kK-1] = 0ull;
    }
    if (tid == k) my_a = (int)((unsigned)(~w0) & 0xffffffffu);
    __syncthreads();
  }
  if (tid < kK && tid < dynk){
    atomicAdd(&cnt[b*kA + my_a], 1);
    atomicMin(&mtch[b*kA + my_a], g);
  }
}

__global__ __launch_bounds__(256) void k_loss(
    const float* __restrict__ f8, const float* __restrict__ f16, const float* __restrict__ f32x,
    const float* __restrict__ gtb, const int* __restrict__ gtc, const int* __restrict__ ngts,
    const float* __restrict__ boxes, const float* __restrict__ objl, const float* __restrict__ b0s,
    const float* __restrict__ bceS, const float* __restrict__ obsA,
    const int* __restrict__ fg, const int* __restrict__ cnt, const int* __restrict__ mtch,
    float* __restrict__ acc){
  int b = blockIdx.y;
  int a = blockIdx.x*256 + threadIdx.x;
  int tid = threadIdx.x;
  __shared__ float4 sg[kG];
  __shared__ int scls[kG];
  if (tid < kG){ sg[tid] = ((const float4*)gtb)[b*kG + tid]; scls[tid] = gtc[b*kG + tid]; }
  __syncthreads();
  float li = 0.0f, lo = 0.0f, lc = 0.0f, nf = 0.0f;
  bool valid = (a < kA);
  int idx = valid ? (b*kA + a) : (b*kA);
  int c = valid ? cnt[idx] : 0;
  float ob = valid ? objl[idx] : 0.0f;
  float4 bx = valid ? ((const float4*)boxes)[idx] : make_float4(0,0,1,1);

  float fgf = 0.0f; int mg = 0;
  if (valid && c == 1){ mg = mtch[idx]; fgf = 1.0f; }
  bool need = valid && (c > 1);
  if (__any(need)){
    if (need){
      int ng = ngts[b];
      float b0 = b0s[idx];
      float obs = obsA[idx];
      int fga = fg[idx];
      float bestc = 3.0e38f; int bg = 0;
      for (int g = 0; g < ng; ++g){
        float iou = pair_iou(sg[g], bx);
        float cl = featv(f8,f16,f32x,b,5+scls[g],a);
        float cst = cost_core(iou, cl, obs, b0, a, sg[g], fga);
        if (cst < bestc){ bestc = cst; bg = g; }   // strict <: first min = jnp.argmin
      }
      mg = bg; fgf = 1.0f;
    }
  }
  if (valid){
    lo = bce(ob, fgf*0.9f);
    if (fgf > 0.0f){
      nf = 1.0f;
      float4 r = sg[mg];
      float piou = pair_iou(r, bx);
      float tlx = fmaxf(bx.x - bx.z*0.5f, r.x - r.z*0.5f);
      float tly = fmaxf(bx.y - bx.w*0.5f, r.y - r.w*0.5f);
      float brx = fminf(bx.x + bx.z*0.5f, r.x + r.z*0.5f);
      float bry = fminf(bx.y + bx.w*0.5f, r.y + r.w*0.5f);
      float inter = (tlx < brx && tly < bry) ? (brx-tlx)*(bry-tly) : 0.0f;
      float un = bx.z*bx.w + r.z*r.w - inter;
      float iou = fdiv(inter, un + 1e-16f);
      li = 1.0f - iou*iou;
      int tc = scls[mg];
      float cl_tc = featv(f8,f16,f32x,b,5+tc,a);
      lc = bceS[idx] - piou * cl_tc;   // linearity of bce in target
    }
  }
  for (int off = 32; off > 0; off >>= 1){
    li += __shfl_down(li, off, 64);
    lo += __shfl_down(lo, off, 64);
    lc += __shfl_down(lc, off, 64);
    nf += __shfl_down(nf, off, 64);
  }
  __shared__ float4 wred[4];
  int wid = tid >> 6;
  if ((tid & 63) == 0) wred[wid] = make_float4(li, lo, lc, nf);
  __syncthreads();
  if (tid == 0){
    float4 t = wred[0];
    for (int w = 1; w < 4; ++w){
      float4 o = wred[w];
      t.x += o.x; t.y += o.y; t.z += o.z; t.w += o.w;
    }
    atomicAdd(&acc[0], t.x);
    atomicAdd(&acc[1], t.y);
    atomicAdd(&acc[2], t.z);
    atomicAdd(&acc[3], t.w);
  }
}

__global__ void k_final(const float* __restrict__ acc, float* __restrict__ out){
  out[0] = (5.0f*acc[0] + acc[1] + acc[2]) / fmaxf(acc[3], 1.0f);
}

extern "C" void kernel_launch(void* const* d_in, const int* in_sizes, int n_in,
                              void* d_out, int out_size, void* d_ws, size_t ws_size,
                              hipStream_t stream) {
  (void)in_sizes; (void)n_in; (void)out_size; (void)ws_size;
  const float* f8   = (const float*)d_in[0];
  const float* f16  = (const float*)d_in[1];
  const float* f32x = (const float*)d_in[2];
  const float* gtb  = (const float*)d_in[3];
  const int*   gtc  = (const int*)d_in[4];
  const int*   ngts = (const int*)d_in[5];
  float* out = (float*)d_out;

  const size_t BA = (size_t)kB*kA;
  float* ws    = (float*)d_ws;
  float* boxes = ws;                              // 4*BA f32
  float* objl  = boxes + BA*4;
  float* b0s   = objl  + BA;
  float* bceS  = b0s   + BA;
  float* obsA  = bceS  + BA;
  int*   fg    = (int*)(obsA + BA);
  int*   cnt   = fg  + BA;
  int*   mtch  = cnt + BA;
  unsigned short* alist = (unsigned short*)(mtch + BA);  // BA u16
  int*   mcnt  = (int*)(alist + BA);              // kB ints
  float* acc   = (float*)(mcnt + kB);             // 4

  dim3 gBA((kA + 255)/256, kB);
  k_zero<<<dim3(1), dim3(64), 0, stream>>>(acc);
  k_decode<<<gBA, dim3(256), 0, stream>>>(f8,f16,f32x,gtb,ngts,boxes,objl,b0s,bceS,obsA,fg,cnt,mtch);
  k_compact<<<dim3(kB), dim3(1024), 0, stream>>>(fg, alist, mcnt);
  k_assign<<<dim3(kB*kG), dim3(256), 0, stream>>>(f8,f16,f32x,gtb,gtc,ngts,boxes,obsA,b0s,fg,alist,mcnt,cnt,mtch);
  k_loss<<<gBA, dim3(256), 0, stream>>>(f8,f16,f32x,gtb,gtc,ngts,boxes,objl,b0s,bceS,obsA,fg,cnt,mtch,acc);
  k_final<<<dim3(1), dim3(1), 0, stream>>>(acc, out);
}

// Round 5
// 231.703 us; speedup vs baseline: 2.0458x; 1.1967x over previous
//
#include <hip/hip_runtime.h>

constexpr int kB = 32;      // batch
constexpr int kA = 8400;    // anchors total (80*80 + 40*40 + 20*20)
constexpr int kG = 60;      // max GTs
constexpr int kC = 80;      // classes
constexpr int kK = 10;      // top-k
constexpr int kNBx = (kA + 255)/256;    // 33
constexpr int kNB = kNBx * kB;          // 1056 loss blocks

// ---- HW-native fast math ----
__device__ __forceinline__ float fexp(float x){ return __expf(x); }
__device__ __forceinline__ float flog(float x){ return __logf(x); }
__device__ __forceinline__ float frcp(float x){ return __builtin_amdgcn_rcpf(x); }
__device__ __forceinline__ float fsqrt(float x){ return __builtin_amdgcn_sqrtf(x); }
__device__ __forceinline__ float fdiv(float a, float b){ return a * __builtin_amdgcn_rcpf(b); }
__device__ __forceinline__ float sigm(float x){ return frcp(1.0f + fexp(-x)); }
__device__ __forceinline__ float bce(float x, float t){
  return fmaxf(x, 0.0f) - x*t + flog(1.0f + fexp(-fabsf(x)));
}

// monotone float -> u32 (total order)
__device__ __forceinline__ unsigned ordbits(float v){
  unsigned u = __float_as_uint(v);
  return (u & 0x80000000u) ? ~u : (u | 0x80000000u);
}
__device__ __forceinline__ float unpackf(unsigned k){
  return __uint_as_float((k & 0x80000000u) ? (k & 0x7fffffffu) : ~k);
}

struct AInfo { int x, y; float st; };
__device__ __forceinline__ AInfo ainfo(int a){
  AInfo r;
  if (a < 6400)      { r.x = a % 80;           r.y = a / 80;           r.st = 8.0f;  }
  else if (a < 8000) { int l = a-6400; r.x = l % 40; r.y = l / 40;     r.st = 16.0f; }
  else               { int l = a-8000; r.x = l % 20; r.y = l / 20;     r.st = 32.0f; }
  return r;
}

__device__ __forceinline__ float featv(const float* __restrict__ f8,
                                       const float* __restrict__ f16,
                                       const float* __restrict__ f32x,
                                       int b, int ch, int a){
  if (a < 6400) return f8 [(b*85 + ch)*6400 + a];
  if (a < 8000) return f16[(b*85 + ch)*1600 + (a - 6400)];
  return             f32x[(b*85 + ch)*400  + (a - 8000)];
}

__device__ __forceinline__ float pair_iou(float4 g, float4 p){
  float tlx = fmaxf(g.x - g.z*0.5f, p.x - p.z*0.5f);
  float tly = fmaxf(g.y - g.w*0.5f, p.y - p.w*0.5f);
  float brx = fminf(g.x + g.z*0.5f, p.x + p.z*0.5f);
  float bry = fminf(g.y + g.w*0.5f, p.y + p.w*0.5f);
  float inter = (tlx < brx && tly < bry) ? (brx-tlx)*(bry-tly) : 0.0f;
  return fdiv(inter, g.z*g.w + p.z*p.w - inter + 1e-16f);
}

// cost given precomputed iou and obj sigmoid — shared by k_assign / k_loss
__device__ __forceinline__ float cost_core(float iou, float cl, float obs, float b0sum,
                                           int a, float4 gt, int fg_a){
  AInfo ai = ainfo(a);
  float cx = ((float)ai.x + 0.5f)*ai.st;
  float cy = ((float)ai.y + 0.5f)*ai.st;
  bool in_box = (cx > gt.x - 0.5f*gt.z) && (cx < gt.x + 0.5f*gt.z)
             && (cy > gt.y - 0.5f*gt.w) && (cy < gt.y + 0.5f*gt.w);
  bool in_ctr = (cx > gt.x - 2.5f*ai.st) && (cx < gt.x + 2.5f*ai.st)
             && (cy > gt.y - 2.5f*ai.st) && (cy < gt.y + 2.5f*ai.st);
  float p = fsqrt(sigm(cl) * obs);
  p = fminf(fmaxf(p, 1e-7f), 1.0f - 1e-7f);
  float diff = -flog(p) + flog(1.0f - p);      // bce1 - bce0 at class cls
  float c = b0sum + diff;
  c += 3.0f * (-flog(iou + 1e-8f));
  c += (in_box && in_ctr) ? 0.0f : 100000.0f;
  c += fg_a ? 0.0f : 1000000000.0f;
  return c;
}

__global__ __launch_bounds__(256) void k_decode(
    const float* __restrict__ f8, const float* __restrict__ f16, const float* __restrict__ f32x,
    const float* __restrict__ gtb, const int* __restrict__ ngts,
    float* __restrict__ boxes, float* __restrict__ objl, float* __restrict__ b0s,
    float* __restrict__ bceS, float* __restrict__ obsA,
    int* __restrict__ fg, int* __restrict__ cnt, int* __restrict__ mtch){
  int b = blockIdx.y;
  int tid = threadIdx.x;
  int a = blockIdx.x*256 + tid;
  __shared__ float4 sg[kG];
  if (tid < kG) sg[tid] = ((const float4*)gtb)[b*kG + tid];
  __syncthreads();
  if (a >= kA) return;
  int ng = ngts[b];
  const float* base; int hw, off; float st_; int gx, gy;
  if (a < 6400)      { base=f8;   hw=6400; off=a;        st_=8.0f;  gx=off%80; gy=off/80; }
  else if (a < 8000) { base=f16;  hw=1600; off=a-6400;   st_=16.0f; gx=off%40; gy=off/40; }
  else               { base=f32x; hw=400;  off=a-8000;   st_=32.0f; gx=off%20; gy=off/20; }
  const float* p0 = base + ((size_t)b*85)*hw + off;
  float t0 = p0[0];
  float t1 = p0[(size_t)hw];
  float t2 = p0[(size_t)2*hw];
  float t3 = p0[(size_t)3*hw];
  float ob = p0[(size_t)4*hw];
  float4 bx;
  bx.x = (t0 + (float)gx) * st_;
  bx.y = (t1 + (float)gy) * st_;
  bx.z = fexp(t2) * st_;
  bx.w = fexp(t3) * st_;
  int idx = b*kA + a;
  ((float4*)boxes)[idx] = bx;
  objl[idx] = ob;
  float obs = sigm(ob);
  obsA[idx] = obs;
  float s = 0.0f;    // sum bce0 on geometric-mean prob (cost base)
  float s2 = 0.0f;   // sum bce(cl, 0) (loss_cls via linearity in t)
  const float* pc = p0 + (size_t)5*hw;
  #pragma unroll 4
  for (int c = 0; c < kC; ++c){
    float cl = pc[(size_t)c*hw];
    float p = fsqrt(sigm(cl)*obs);
    p = fminf(fmaxf(p, 1e-7f), 1.0f - 1e-7f);
    s -= flog(1.0f - p);
    s2 += fmaxf(cl, 0.0f) + flog(1.0f + fexp(-fabsf(cl)));
  }
  b0s[idx] = s;
  bceS[idx] = s2;
  float cx = ((float)gx + 0.5f)*st_;
  float cy = ((float)gy + 0.5f)*st_;
  int f = 0;
  for (int g = 0; g < ng; ++g){
    float4 gt = sg[g];
    bool in_box = (cx > gt.x - 0.5f*gt.z) && (cx < gt.x + 0.5f*gt.z)
               && (cy > gt.y - 0.5f*gt.w) && (cy < gt.y + 0.5f*gt.w);
    bool in_ctr = (cx > gt.x - 2.5f*st_) && (cx < gt.x + 2.5f*st_)
               && (cy > gt.y - 2.5f*st_) && (cy < gt.y + 2.5f*st_);
    if (in_box || in_ctr){ f = 1; break; }
  }
  fg[idx] = f;
  cnt[idx] = 0;
  mtch[idx] = 0x7fffffff;
}

// ordered compaction of fg anchors: one block per batch; preserves ascending index order
__global__ __launch_bounds__(1024) void k_compact(
    const int* __restrict__ fg, unsigned short* __restrict__ alist, int* __restrict__ mcnt){
  int b = blockIdx.x;
  int tid = threadIdx.x;
  const int CH = 9;                       // ceil(8400/1024)
  int start = tid*CH;
  int myf[CH]; int cl = 0;
  #pragma unroll
  for (int j = 0; j < CH; ++j){
    int a = start + j;
    int f = (a < kA) ? fg[b*kA + a] : 0;
    myf[j] = f; cl += f;
  }
  __shared__ int s1[1024], s2[1024];
  int* cur = s1; int* nxt = s2;
  cur[tid] = cl; __syncthreads();
  for (int off = 1; off < 1024; off <<= 1){
    int v = cur[tid];
    if (tid >= off) v += cur[tid - off];
    nxt[tid] = v; __syncthreads();
    int* t = cur; cur = nxt; nxt = t;
  }
  int o = cur[tid] - cl;                  // exclusive prefix
  unsigned short* out = alist + (size_t)b*kA;
  #pragma unroll
  for (int j = 0; j < CH; ++j){
    int a = start + j;
    if (a < kA && myf[j]) out[o++] = (unsigned short)a;
  }
  if (tid == 1023) mcnt[b] = cur[tid];
}

__global__ __launch_bounds__(256) void k_assign(
    const float* __restrict__ f8, const float* __restrict__ f16, const float* __restrict__ f32x,
    const float* __restrict__ gtb, const int* __restrict__ gtc, const int* __restrict__ ngts,
    const float* __restrict__ boxes, const float* __restrict__ obsA, const float* __restrict__ b0s,
    const int* __restrict__ fg, const unsigned short* __restrict__ alist, const int* __restrict__ mcnt,
    int* __restrict__ cnt, int* __restrict__ mtch){
  int b = blockIdx.x / kG;
  int g = blockIdx.x % kG;
  if (g >= ngts[b]) return;     // vmask (block-uniform)
  int tid = threadIdx.x;
  int lane = tid & 63, wid = tid >> 6;
  float4 gt = ((const float4*)gtb)[b*kG + g];
  int cls = gtc[b*kG + g];
  const float4* bx4 = (const float4*)boxes;
  const float* c8  = f8   + ((size_t)b*85 + 5 + cls)*6400;
  const float* c16 = f16  + ((size_t)b*85 + 5 + cls)*1600;
  const float* c32 = f32x + ((size_t)b*85 + 5 + cls)*400;
  int m = mcnt[b];
  bool full = (m < kK);          // fallback: scan everything (exactness guard)
  int len = full ? kA : m;
  const unsigned short* al = alist + (size_t)b*kA;
  __shared__ unsigned long long wk[4];

  unsigned long long k1[kK], k2[kK];
  #pragma unroll
  for (int i = 0; i < kK; ++i){ k1[i] = 0ull; k2[i] = 0ull; }

  for (int i = tid; i < len; i += 256){
    int a = full ? i : (int)al[i];
    int idx = b*kA + a;
    float4 bx = bx4[idx];
    float iou = pair_iou(gt, bx);
    int fga = full ? fg[idx] : 1;
    float v = fga ? iou : 0.0f;
    unsigned long long key1 = ((unsigned long long)ordbits(v) << 32) | (unsigned)(~a);
    if (key1 > k1[kK-1]){
      k1[kK-1] = key1;
      #pragma unroll
      for (int i2 = kK-1; i2 > 0; --i2)
        if (k1[i2] > k1[i2-1]){ unsigned long long t = k1[i2]; k1[i2] = k1[i2-1]; k1[i2-1] = t; }
    }
    float cl = (a < 6400) ? c8[a] : (a < 8000) ? c16[a-6400] : c32[a-8000];
    float c = cost_core(iou, cl, obsA[idx], b0s[idx], a, gt, fga);
    unsigned long long key2 = ~(((unsigned long long)ordbits(c) << 32) | (unsigned)a);
    if (key2 > k2[kK-1]){
      k2[kK-1] = key2;
      #pragma unroll
      for (int i2 = kK-1; i2 > 0; --i2)
        if (k2[i2] > k2[i2-1]){ unsigned long long t = k2[i2]; k2[i2] = k2[i2-1]; k2[i2-1] = t; }
    }
  }

  // extract global top-10 of pass-1 (sum of values, descending order)
  float ksum = 0.0f;
  for (int k = 0; k < kK; ++k){
    unsigned long long best = k1[0];
    #pragma unroll
    for (int off = 32; off; off >>= 1){
      unsigned long long o = __shfl_xor(best, off, 64);
      if (o > best) best = o;
    }
    if (lane == 0) wk[wid] = best;
    __syncthreads();
    unsigned long long w0 = wk[0];
    if (wk[1] > w0) w0 = wk[1];
    if (wk[2] > w0) w0 = wk[2];
    if (wk[3] > w0) w0 = wk[3];
    if (k1[0] == w0){                     // unique keys -> exactly one pop
      #pragma unroll
      for (int i = 0; i < kK-1; ++i) k1[i] = k1[i+1];
      k1[kK-1] = 0ull;
    }
    ksum += unpackf((unsigned)(w0 >> 32));
    __syncthreads();
  }
  int dynk = max((int)ksum, 1);

  // extract global bottom-10 of cost
  int my_a = -1;
  for (int k = 0; k < kK; ++k){
    unsigned long long best = k2[0];
    #pragma unroll
    for (int off = 32; off; off >>= 1){
      unsigned long long o = __shfl_xor(best, off, 64);
      if (o > best) best = o;
    }
    if (lane == 0) wk[wid] = best;
    __syncthreads();
    unsigned long long w0 = wk[0];
    if (wk[1] > w0) w0 = wk[1];
    if (wk[2] > w0) w0 = wk[2];
    if (wk[3] > w0) w0 = wk[3];
    if (k2[0] == w0){
      #pragma unroll
      for (int i = 0; i < kK-1; ++i) k2[i] = k2[i+1];
      k2[kK-1] = 0ull;
    }
    if (tid == k) my_a = (int)((unsigned)(~w0) & 0xffffffffu);
    __syncthreads();
  }
  if (tid < kK && tid < dynk){
    atomicAdd(&cnt[b*kA + my_a], 1);     // scattered addresses: no same-line contention
    atomicMin(&mtch[b*kA + my_a], g);
  }
}

__global__ __launch_bounds__(256) void k_loss(
    const float* __restrict__ f8, const float* __restrict__ f16, const float* __restrict__ f32x,
    const float* __restrict__ gtb, const int* __restrict__ gtc, const int* __restrict__ ngts,
    const float* __restrict__ boxes, const float* __restrict__ objl, const float* __restrict__ b0s,
    const float* __restrict__ bceS, const float* __restrict__ obsA,
    const int* __restrict__ fg, const int* __restrict__ cnt, const int* __restrict__ mtch,
    float4* __restrict__ pacc){
  int b = blockIdx.y;
  int a = blockIdx.x*256 + threadIdx.x;
  int tid = threadIdx.x;
  __shared__ float4 sg[kG];
  __shared__ int scls[kG];
  if (tid < kG){ sg[tid] = ((const float4*)gtb)[b*kG + tid]; scls[tid] = gtc[b*kG + tid]; }
  __syncthreads();
  float li = 0.0f, lo = 0.0f, lc = 0.0f, nf = 0.0f;
  bool valid = (a < kA);
  int idx = valid ? (b*kA + a) : (b*kA);
  int c = valid ? cnt[idx] : 0;
  float ob = valid ? objl[idx] : 0.0f;
  float4 bx = valid ? ((const float4*)boxes)[idx] : make_float4(0,0,1,1);

  float fgf = 0.0f; int mg = 0;
  if (valid && c == 1){ mg = mtch[idx]; fgf = 1.0f; }
  bool need = valid && (c > 1);
  if (__any(need)){
    if (need){
      int ng = ngts[b];
      float b0 = b0s[idx];
      float obs = obsA[idx];
      int fga = fg[idx];
      float bestc = 3.0e38f; int bg = 0;
      for (int g = 0; g < ng; ++g){
        float iou = pair_iou(sg[g], bx);
        float cl = featv(f8,f16,f32x,b,5+scls[g],a);
        float cst = cost_core(iou, cl, obs, b0, a, sg[g], fga);
        if (cst < bestc){ bestc = cst; bg = g; }   // strict <: first min = jnp.argmin
      }
      mg = bg; fgf = 1.0f;
    }
  }
  if (valid){
    lo = bce(ob, fgf*0.9f);
    if (fgf > 0.0f){
      nf = 1.0f;
      float4 r = sg[mg];
      float piou = pair_iou(r, bx);
      float tlx = fmaxf(bx.x - bx.z*0.5f, r.x - r.z*0.5f);
      float tly = fmaxf(bx.y - bx.w*0.5f, r.y - r.w*0.5f);
      float brx = fminf(bx.x + bx.z*0.5f, r.x + r.z*0.5f);
      float bry = fminf(bx.y + bx.w*0.5f, r.y + r.w*0.5f);
      float inter = (tlx < brx && tly < bry) ? (brx-tlx)*(bry-tly) : 0.0f;
      float un = bx.z*bx.w + r.z*r.w - inter;
      float iou = fdiv(inter, un + 1e-16f);
      li = 1.0f - iou*iou;
      int tc = scls[mg];
      float cl_tc = featv(f8,f16,f32x,b,5+tc,a);
      lc = bceS[idx] - piou * cl_tc;   // linearity of bce in target
    }
  }
  for (int off = 32; off > 0; off >>= 1){
    li += __shfl_down(li, off, 64);
    lo += __shfl_down(lo, off, 64);
    lc += __shfl_down(lc, off, 64);
    nf += __shfl_down(nf, off, 64);
  }
  __shared__ float4 wred[4];
  int wid = tid >> 6;
  if ((tid & 63) == 0) wred[wid] = make_float4(li, lo, lc, nf);
  __syncthreads();
  if (tid == 0){
    float4 t = wred[0];
    for (int w = 1; w < 4; ++w){
      float4 o = wred[w];
      t.x += o.x; t.y += o.y; t.z += o.z; t.w += o.w;
    }
    // per-block partial to a DISTINCT slot — no atomics, no same-line contention
    pacc[blockIdx.y * gridDim.x + blockIdx.x] = t;
  }
}

__global__ __launch_bounds__(256) void k_final(
    const float4* __restrict__ pacc, float* __restrict__ out){
  int tid = threadIdx.x;
  float li = 0.0f, lo = 0.0f, lc = 0.0f, nf = 0.0f;
  for (int i = tid; i < kNB; i += 256){
    float4 p = pacc[i];
    li += p.x; lo += p.y; lc += p.z; nf += p.w;
  }
  for (int off = 32; off > 0; off >>= 1){
    li += __shfl_down(li, off, 64);
    lo += __shfl_down(lo, off, 64);
    lc += __shfl_down(lc, off, 64);
    nf += __shfl_down(nf, off, 64);
  }
  __shared__ float4 wred[4];
  int wid = tid >> 6;
  if ((tid & 63) == 0) wred[wid] = make_float4(li, lo, lc, nf);
  __syncthreads();
  if (tid == 0){
    float4 t = wred[0];
    for (int w = 1; w < 4; ++w){
      float4 o = wred[w];
      t.x += o.x; t.y += o.y; t.z += o.z; t.w += o.w;
    }
    out[0] = (5.0f*t.x + t.y + t.z) * frcp(fmaxf(t.w, 1.0f));
  }
}

extern "C" void kernel_launch(void* const* d_in, const int* in_sizes, int n_in,
                              void* d_out, int out_size, void* d_ws, size_t ws_size,
                              hipStream_t stream) {
  (void)in_sizes; (void)n_in; (void)out_size; (void)ws_size;
  const float* f8   = (const float*)d_in[0];
  const float* f16  = (const float*)d_in[1];
  const float* f32x = (const float*)d_in[2];
  const float* gtb  = (const float*)d_in[3];
  const int*   gtc  = (const int*)d_in[4];
  const int*   ngts = (const int*)d_in[5];
  float* out = (float*)d_out;

  const size_t BA = (size_t)kB*kA;
  float* ws    = (float*)d_ws;
  float* boxes = ws;                              // 4*BA f32
  float* objl  = boxes + BA*4;
  float* b0s   = objl  + BA;
  float* bceS  = b0s   + BA;
  float* obsA  = bceS  + BA;
  int*   fg    = (int*)(obsA + BA);
  int*   cnt   = fg  + BA;
  int*   mtch  = cnt + BA;
  unsigned short* alist = (unsigned short*)(mtch + BA);  // BA u16
  int*   mcnt  = (int*)(alist + BA);              // kB ints
  float4* pacc = (float4*)(mcnt + kB);            // kNB float4 partials

  dim3 gBA(kNBx, kB);
  k_decode<<<gBA, dim3(256), 0, stream>>>(f8,f16,f32x,gtb,ngts,boxes,objl,b0s,bceS,obsA,fg,cnt,mtch);
  k_compact<<<dim3(kB), dim3(1024), 0, stream>>>(fg, alist, mcnt);
  k_assign<<<dim3(kB*kG), dim3(256), 0, stream>>>(f8,f16,f32x,gtb,gtc,ngts,boxes,obsA,b0s,fg,alist,mcnt,cnt,mtch);
  k_loss<<<gBA, dim3(256), 0, stream>>>(f8,f16,f32x,gtb,gtc,ngts,boxes,objl,b0s,bceS,obsA,fg,cnt,mtch,pacc);
  k_final<<<dim3(1), dim3(256), 0, stream>>>(pacc, out);
}

// Round 6
// 216.333 us; speedup vs baseline: 2.1912x; 1.0710x over previous
//
#include <hip/hip_runtime.h>

constexpr int kB = 32;      // batch
constexpr int kA = 8400;    // anchors total (80*80 + 40*40 + 20*20)
constexpr int kG = 60;      // max GTs
constexpr int kC = 80;      // classes
constexpr int kK = 10;      // top-k
constexpr int kNBx = (kA + 255)/256;    // 33
constexpr int kNB = kNBx * kB;          // 1056 loss blocks

// ---- HW-native fast math ----
__device__ __forceinline__ float fexp(float x){ return __expf(x); }
__device__ __forceinline__ float flog(float x){ return __logf(x); }
__device__ __forceinline__ float frcp(float x){ return __builtin_amdgcn_rcpf(x); }
__device__ __forceinline__ float frsq(float x){ return __builtin_amdgcn_rsqf(x); }
__device__ __forceinline__ float fsqrt(float x){ return __builtin_amdgcn_sqrtf(x); }
__device__ __forceinline__ float fdiv(float a, float b){ return a * __builtin_amdgcn_rcpf(b); }
__device__ __forceinline__ float sigm(float x){ return frcp(1.0f + fexp(-x)); }
__device__ __forceinline__ float bce(float x, float t){
  return fmaxf(x, 0.0f) - x*t + flog(1.0f + fexp(-fabsf(x)));
}

// monotone float -> u32 (total order)
__device__ __forceinline__ unsigned ordbits(float v){
  unsigned u = __float_as_uint(v);
  return (u & 0x80000000u) ? ~u : (u | 0x80000000u);
}
__device__ __forceinline__ float unpackf(unsigned k){
  return __uint_as_float((k & 0x80000000u) ? (k & 0x7fffffffu) : ~k);
}

struct AInfo { int x, y; float st; };
__device__ __forceinline__ AInfo ainfo(int a){
  AInfo r;
  if (a < 6400)      { r.x = a % 80;           r.y = a / 80;           r.st = 8.0f;  }
  else if (a < 8000) { int l = a-6400; r.x = l % 40; r.y = l / 40;     r.st = 16.0f; }
  else               { int l = a-8000; r.x = l % 20; r.y = l / 20;     r.st = 32.0f; }
  return r;
}

__device__ __forceinline__ float featv(const float* __restrict__ f8,
                                       const float* __restrict__ f16,
                                       const float* __restrict__ f32x,
                                       int b, int ch, int a){
  if (a < 6400) return f8 [(b*85 + ch)*6400 + a];
  if (a < 8000) return f16[(b*85 + ch)*1600 + (a - 6400)];
  return             f32x[(b*85 + ch)*400  + (a - 8000)];
}

__device__ __forceinline__ float pair_iou(float4 g, float4 p){
  float tlx = fmaxf(g.x - g.z*0.5f, p.x - p.z*0.5f);
  float tly = fmaxf(g.y - g.w*0.5f, p.y - p.w*0.5f);
  float brx = fminf(g.x + g.z*0.5f, p.x + p.z*0.5f);
  float bry = fminf(g.y + g.w*0.5f, p.y + p.w*0.5f);
  float inter = (tlx < brx && tly < bry) ? (brx-tlx)*(bry-tly) : 0.0f;
  return fdiv(inter, g.z*g.w + p.z*p.w - inter + 1e-16f);
}

// cost given precomputed iou and obj sigmoid — shared by k_assign / k_loss
__device__ __forceinline__ float cost_core(float iou, float cl, float obs, float b0sum,
                                           int a, float4 gt, int fg_a){
  AInfo ai = ainfo(a);
  float cx = ((float)ai.x + 0.5f)*ai.st;
  float cy = ((float)ai.y + 0.5f)*ai.st;
  bool in_box = (cx > gt.x - 0.5f*gt.z) && (cx < gt.x + 0.5f*gt.z)
             && (cy > gt.y - 0.5f*gt.w) && (cy < gt.y + 0.5f*gt.w);
  bool in_ctr = (cx > gt.x - 2.5f*ai.st) && (cx < gt.x + 2.5f*ai.st)
             && (cy > gt.y - 2.5f*ai.st) && (cy < gt.y + 2.5f*ai.st);
  float p = fsqrt(sigm(cl) * obs);
  p = fminf(fmaxf(p, 1e-7f), 1.0f - 1e-7f);
  float diff = -flog(p) + flog(1.0f - p);      // bce1 - bce0 at class cls
  float c = b0sum + diff;
  c += 3.0f * (-flog(iou + 1e-8f));
  c += (in_box && in_ctr) ? 0.0f : 100000.0f;
  c += fg_a ? 0.0f : 1000000000.0f;
  return c;
}

__global__ __launch_bounds__(256) void k_decode(
    const float* __restrict__ f8, const float* __restrict__ f16, const float* __restrict__ f32x,
    const float* __restrict__ gtb, const int* __restrict__ ngts,
    float* __restrict__ boxes, float* __restrict__ objl, float* __restrict__ b0s,
    float* __restrict__ bceS, float* __restrict__ obsA,
    int* __restrict__ fg, int* __restrict__ cnt, int* __restrict__ mtch){
  int b = blockIdx.y;
  int tid = threadIdx.x;
  int a = blockIdx.x*256 + tid;
  __shared__ float4 sg[kG];
  if (tid < kG) sg[tid] = ((const float4*)gtb)[b*kG + tid];
  __syncthreads();
  if (a >= kA) return;
  int ng = ngts[b];
  const float* base; int hw, off; float st_; int gx, gy;
  if (a < 6400)      { base=f8;   hw=6400; off=a;        st_=8.0f;  gx=off%80; gy=off/80; }
  else if (a < 8000) { base=f16;  hw=1600; off=a-6400;   st_=16.0f; gx=off%40; gy=off/40; }
  else               { base=f32x; hw=400;  off=a-8000;   st_=32.0f; gx=off%20; gy=off/20; }
  const float* p0 = base + ((size_t)b*85)*hw + off;
  float t0 = p0[0];
  float t1 = p0[(size_t)hw];
  float t2 = p0[(size_t)2*hw];
  float t3 = p0[(size_t)3*hw];
  float ob = p0[(size_t)4*hw];
  float4 bx;
  bx.x = (t0 + (float)gx) * st_;
  bx.y = (t1 + (float)gy) * st_;
  bx.z = fexp(t2) * st_;
  bx.w = fexp(t3) * st_;
  int idx = b*kA + a;
  ((float4*)boxes)[idx] = bx;
  objl[idx] = ob;
  float obs = sigm(ob);
  obsA[idx] = obs;
  // ---- class loop, transcendental-minimized ----
  // sigm(cl)*obs = obs / v, v = 1 + e^-cl  =>  p = sqrt(obs) * rsqrt(v)
  // bce(cl,0) = softplus(cl) = cl + log(v)
  // logs grouped over 8 classes: sum(-log(1-p)) = -log(prod(1-p)); sum(log v) = log(prod v)
  float so = fsqrt(obs);
  float s = 0.0f;        // sum bce0 on geometric-mean prob (cost base)
  float sumCl = 0.0f;    // sum of class logits
  float slogv = 0.0f;    // sum log(v)
  const float* pc = p0 + (size_t)5*hw;
  #pragma unroll 2
  for (int grp = 0; grp < kC/8; ++grp){
    float prodS = 1.0f, prodV = 1.0f;
    #pragma unroll
    for (int j = 0; j < 8; ++j){
      float cl = pc[(size_t)(grp*8 + j)*hw];
      float u = fexp(-cl);
      float v = 1.0f + u;
      float p = so * frsq(v);
      p = fminf(fmaxf(p, 1e-7f), 1.0f - 1e-7f);
      prodS *= (1.0f - p);
      prodV *= v;
      sumCl += cl;
    }
    s -= flog(prodS);
    slogv += flog(prodV);
  }
  b0s[idx] = s;
  bceS[idx] = sumCl + slogv;
  float cx = ((float)gx + 0.5f)*st_;
  float cy = ((float)gy + 0.5f)*st_;
  int f = 0;
  for (int g = 0; g < ng; ++g){
    float4 gt = sg[g];
    bool in_box = (cx > gt.x - 0.5f*gt.z) && (cx < gt.x + 0.5f*gt.z)
               && (cy > gt.y - 0.5f*gt.w) && (cy < gt.y + 0.5f*gt.w);
    bool in_ctr = (cx > gt.x - 2.5f*st_) && (cx < gt.x + 2.5f*st_)
               && (cy > gt.y - 2.5f*st_) && (cy < gt.y + 2.5f*st_);
    if (in_box || in_ctr){ f = 1; break; }
  }
  fg[idx] = f;
  cnt[idx] = 0;
  mtch[idx] = 0x7fffffff;
}

// ordered compaction of fg anchors: one block per batch; preserves ascending index order
__global__ __launch_bounds__(1024) void k_compact(
    const int* __restrict__ fg, unsigned short* __restrict__ alist, int* __restrict__ mcnt){
  int b = blockIdx.x;
  int tid = threadIdx.x;
  const int CH = 9;                       // ceil(8400/1024)
  int start = tid*CH;
  int myf[CH]; int cl = 0;
  #pragma unroll
  for (int j = 0; j < CH; ++j){
    int a = start + j;
    int f = (a < kA) ? fg[b*kA + a] : 0;
    myf[j] = f; cl += f;
  }
  __shared__ int s1[1024], s2[1024];
  int* cur = s1; int* nxt = s2;
  cur[tid] = cl; __syncthreads();
  for (int off = 1; off < 1024; off <<= 1){
    int v = cur[tid];
    if (tid >= off) v += cur[tid - off];
    nxt[tid] = v; __syncthreads();
    int* t = cur; cur = nxt; nxt = t;
  }
  int o = cur[tid] - cl;                  // exclusive prefix
  unsigned short* out = alist + (size_t)b*kA;
  #pragma unroll
  for (int j = 0; j < CH; ++j){
    int a = start + j;
    if (a < kA && myf[j]) out[o++] = (unsigned short)a;
  }
  if (tid == 1023) mcnt[b] = cur[tid];
}

__global__ __launch_bounds__(256) void k_assign(
    const float* __restrict__ f8, const float* __restrict__ f16, const float* __restrict__ f32x,
    const float* __restrict__ gtb, const int* __restrict__ gtc, const int* __restrict__ ngts,
    const float* __restrict__ boxes, const float* __restrict__ obsA, const float* __restrict__ b0s,
    const int* __restrict__ fg, const unsigned short* __restrict__ alist, const int* __restrict__ mcnt,
    int* __restrict__ cnt, int* __restrict__ mtch){
  int b = blockIdx.x / kG;
  int g = blockIdx.x % kG;
  if (g >= ngts[b]) return;     // vmask (block-uniform)
  int tid = threadIdx.x;
  int lane = tid & 63, wid = tid >> 6;
  float4 gt = ((const float4*)gtb)[b*kG + g];
  int cls = gtc[b*kG + g];
  const float4* bx4 = (const float4*)boxes;
  const float* c8  = f8   + ((size_t)b*85 + 5 + cls)*6400;
  const float* c16 = f16  + ((size_t)b*85 + 5 + cls)*1600;
  const float* c32 = f32x + ((size_t)b*85 + 5 + cls)*400;
  int m = mcnt[b];
  bool full = (m < kK);          // fallback: scan everything (exactness guard)
  int len = full ? kA : m;
  const unsigned short* al = alist + (size_t)b*kA;
  __shared__ unsigned long long wk[4];

  unsigned long long k1[kK], k2[kK];
  #pragma unroll
  for (int i = 0; i < kK; ++i){ k1[i] = 0ull; k2[i] = 0ull; }

  for (int i = tid; i < len; i += 256){
    int a = full ? i : (int)al[i];
    int idx = b*kA + a;
    float4 bx = bx4[idx];
    float iou = pair_iou(gt, bx);
    int fga = full ? fg[idx] : 1;
    float v = fga ? iou : 0.0f;
    unsigned long long key1 = ((unsigned long long)ordbits(v) << 32) | (unsigned)(~a);
    if (key1 > k1[kK-1]){
      k1[kK-1] = key1;
      #pragma unroll
      for (int i2 = kK-1; i2 > 0; --i2)
        if (k1[i2] > k1[i2-1]){ unsigned long long t = k1[i2]; k1[i2] = k1[i2-1]; k1[i2-1] = t; }
    }
    float cl = (a < 6400) ? c8[a] : (a < 8000) ? c16[a-6400] : c32[a-8000];
    float c = cost_core(iou, cl, obsA[idx], b0s[idx], a, gt, fga);
    unsigned long long key2 = ~(((unsigned long long)ordbits(c) << 32) | (unsigned)a);
    if (key2 > k2[kK-1]){
      k2[kK-1] = key2;
      #pragma unroll
      for (int i2 = kK-1; i2 > 0; --i2)
        if (k2[i2] > k2[i2-1]){ unsigned long long t = k2[i2]; k2[i2] = k2[i2-1]; k2[i2-1] = t; }
    }
  }

  // extract global top-10 of pass-1 (sum of values, descending order)
  float ksum = 0.0f;
  for (int k = 0; k < kK; ++k){
    unsigned long long best = k1[0];
    #pragma unroll
    for (int off = 32; off; off >>= 1){
      unsigned long long o = __shfl_xor(best, off, 64);
      if (o > best) best = o;
    }
    if (lane == 0) wk[wid] = best;
    __syncthreads();
    unsigned long long w0 = wk[0];
    if (wk[1] > w0) w0 = wk[1];
    if (wk[2] > w0) w0 = wk[2];
    if (wk[3] > w0) w0 = wk[3];
    if (k1[0] == w0){                     // unique keys -> exactly one pop
      #pragma unroll
      for (int i = 0; i < kK-1; ++i) k1[i] = k1[i+1];
      k1[kK-1] = 0ull;
    }
    ksum += unpackf((unsigned)(w0 >> 32));
    __syncthreads();
  }
  int dynk = max((int)ksum, 1);

  // extract global bottom-10 of cost
  int my_a = -1;
  for (int k = 0; k < kK; ++k){
    unsigned long long best = k2[0];
    #pragma unroll
    for (int off = 32; off; off >>= 1){
      unsigned long long o = __shfl_xor(best, off, 64);
      if (o > best) best = o;
    }
    if (lane == 0) wk[wid] = best;
    __syncthreads();
    unsigned long long w0 = wk[0];
    if (wk[1] > w0) w0 = wk[1];
    if (wk[2] > w0) w0 = wk[2];
    if (wk[3] > w0) w0 = wk[3];
    if (k2[0] == w0){
      #pragma unroll
      for (int i = 0; i < kK-1; ++i) k2[i] = k2[i+1];
      k2[kK-1] = 0ull;
    }
    if (tid == k) my_a = (int)((unsigned)(~w0) & 0xffffffffu);
    __syncthreads();
  }
  if (tid < kK && tid < dynk){
    atomicAdd(&cnt[b*kA + my_a], 1);     // scattered addresses: no same-line contention
    atomicMin(&mtch[b*kA + my_a], g);
  }
}

__global__ __launch_bounds__(256) void k_loss(
    const float* __restrict__ f8, const float* __restrict__ f16, const float* __restrict__ f32x,
    const float* __restrict__ gtb, const int* __restrict__ gtc, const int* __restrict__ ngts,
    const float* __restrict__ boxes, const float* __restrict__ objl, const float* __restrict__ b0s,
    const float* __restrict__ bceS, const float* __restrict__ obsA,
    const int* __restrict__ fg, const int* __restrict__ cnt, const int* __restrict__ mtch,
    float4* __restrict__ pacc){
  int b = blockIdx.y;
  int a = blockIdx.x*256 + threadIdx.x;
  int tid = threadIdx.x;
  __shared__ float4 sg[kG];
  __shared__ int scls[kG];
  if (tid < kG){ sg[tid] = ((const float4*)gtb)[b*kG + tid]; scls[tid] = gtc[b*kG + tid]; }
  __syncthreads();
  float li = 0.0f, lo = 0.0f, lc = 0.0f, nf = 0.0f;
  bool valid = (a < kA);
  int idx = valid ? (b*kA + a) : (b*kA);
  int c = valid ? cnt[idx] : 0;
  float ob = valid ? objl[idx] : 0.0f;
  float4 bx = valid ? ((const float4*)boxes)[idx] : make_float4(0,0,1,1);

  float fgf = 0.0f; int mg = 0;
  if (valid && c == 1){ mg = mtch[idx]; fgf = 1.0f; }
  bool need = valid && (c > 1);
  if (__any(need)){
    if (need){
      int ng = ngts[b];
      float b0 = b0s[idx];
      float obs = obsA[idx];
      int fga = fg[idx];
      float bestc = 3.0e38f; int bg = 0;
      for (int g = 0; g < ng; ++g){
        float iou = pair_iou(sg[g], bx);
        float cl = featv(f8,f16,f32x,b,5+scls[g],a);
        float cst = cost_core(iou, cl, obs, b0, a, sg[g], fga);
        if (cst < bestc){ bestc = cst; bg = g; }   // strict <: first min = jnp.argmin
      }
      mg = bg; fgf = 1.0f;
    }
  }
  if (valid){
    lo = bce(ob, fgf*0.9f);
    if (fgf > 0.0f){
      nf = 1.0f;
      float4 r = sg[mg];
      float piou = pair_iou(r, bx);
      float tlx = fmaxf(bx.x - bx.z*0.5f, r.x - r.z*0.5f);
      float tly = fmaxf(bx.y - bx.w*0.5f, r.y - r.w*0.5f);
      float brx = fminf(bx.x + bx.z*0.5f, r.x + r.z*0.5f);
      float bry = fminf(bx.y + bx.w*0.5f, r.y + r.w*0.5f);
      float inter = (tlx < brx && tly < bry) ? (brx-tlx)*(bry-tly) : 0.0f;
      float un = bx.z*bx.w + r.z*r.w - inter;
      float iou = fdiv(inter, un + 1e-16f);
      li = 1.0f - iou*iou;
      int tc = scls[mg];
      float cl_tc = featv(f8,f16,f32x,b,5+tc,a);
      lc = bceS[idx] - piou * cl_tc;   // linearity of bce in target
    }
  }
  for (int off = 32; off > 0; off >>= 1){
    li += __shfl_down(li, off, 64);
    lo += __shfl_down(lo, off, 64);
    lc += __shfl_down(lc, off, 64);
    nf += __shfl_down(nf, off, 64);
  }
  __shared__ float4 wred[4];
  int wid = tid >> 6;
  if ((tid & 63) == 0) wred[wid] = make_float4(li, lo, lc, nf);
  __syncthreads();
  if (tid == 0){
    float4 t = wred[0];
    for (int w = 1; w < 4; ++w){
      float4 o = wred[w];
      t.x += o.x; t.y += o.y; t.z += o.z; t.w += o.w;
    }
    pacc[blockIdx.y * gridDim.x + blockIdx.x] = t;
  }
}

__global__ __launch_bounds__(256) void k_final(
    const float4* __restrict__ pacc, float* __restrict__ out){
  int tid = threadIdx.x;
  float li = 0.0f, lo = 0.0f, lc = 0.0f, nf = 0.0f;
  for (int i = tid; i < kNB; i += 256){
    float4 p = pacc[i];
    li += p.x; lo += p.y; lc += p.z; nf += p.w;
  }
  for (int off = 32; off > 0; off >>= 1){
    li += __shfl_down(li, off, 64);
    lo += __shfl_down(lo, off, 64);
    lc += __shfl_down(lc, off, 64);
    nf += __shfl_down(nf, off, 64);
  }
  __shared__ float4 wred[4];
  int wid = tid >> 6;
  if ((tid & 63) == 0) wred[wid] = make_float4(li, lo, lc, nf);
  __syncthreads();
  if (tid == 0){
    float4 t = wred[0];
    for (int w = 1; w < 4; ++w){
      float4 o = wred[w];
      t.x += o.x; t.y += o.y; t.z += o.z; t.w += o.w;
    }
    out[0] = (5.0f*t.x + t.y + t.z) * frcp(fmaxf(t.w, 1.0f));
  }
}

extern "C" void kernel_launch(void* const* d_in, const int* in_sizes, int n_in,
                              void* d_out, int out_size, void* d_ws, size_t ws_size,
                              hipStream_t stream) {
  (void)in_sizes; (void)n_in; (void)out_size; (void)ws_size;
  const float* f8   = (const float*)d_in[0];
  const float* f16  = (const float*)d_in[1];
  const float* f32x = (const float*)d_in[2];
  const float* gtb  = (const float*)d_in[3];
  const int*   gtc  = (const int*)d_in[4];
  const int*   ngts = (const int*)d_in[5];
  float* out = (float*)d_out;

  const size_t BA = (size_t)kB*kA;
  float* ws    = (float*)d_ws;
  float* boxes = ws;                              // 4*BA f32
  float* objl  = boxes + BA*4;
  float* b0s   = objl  + BA;
  float* bceS  = b0s   + BA;
  float* obsA  = bceS  + BA;
  int*   fg    = (int*)(obsA + BA);
  int*   cnt   = fg  + BA;
  int*   mtch  = cnt + BA;
  unsigned short* alist = (unsigned short*)(mtch + BA);  // BA u16
  int*   mcnt  = (int*)(alist + BA);              // kB ints
  float4* pacc = (float4*)(mcnt + kB);            // kNB float4 partials

  dim3 gBA(kNBx, kB);
  k_decode<<<gBA, dim3(256), 0, stream>>>(f8,f16,f32x,gtb,ngts,boxes,objl,b0s,bceS,obsA,fg,cnt,mtch);
  k_compact<<<dim3(kB), dim3(1024), 0, stream>>>(fg, alist, mcnt);
  k_assign<<<dim3(kB*kG), dim3(256), 0, stream>>>(f8,f16,f32x,gtb,gtc,ngts,boxes,obsA,b0s,fg,alist,mcnt,cnt,mtch);
  k_loss<<<gBA, dim3(256), 0, stream>>>(f8,f16,f32x,gtb,gtc,ngts,boxes,objl,b0s,bceS,obsA,fg,cnt,mtch,pacc);
  k_final<<<dim3(1), dim3(256), 0, stream>>>(pacc, out);
}